// Round 6
// baseline (314.373 us; speedup 1.0000x reference)
//
#include <hip/hip_runtime.h>
#include <math.h>

#define E_N    1536
#define NATOMS 64
#define M_DIM  3456          // 54*64
#define NP     256
#define NQ     384
#define HRSZ   2916          // 54*54

#define W_FP 0.0002f
#define W_FQ 0.0001f
#define W_FO 0.00015f
#define W_FR (1.0f - W_FP - W_FQ - W_FO)

#define N4_RED (E_N*HRSZ/4)      // 1119744
#define TOT_A  (E_N*512)         // 786432 hrd items
#define TOT_C  (NATOMS*640*8)    // 327680 pqpad items
#define GRID_PRE 1024

typedef __attribute__((ext_vector_type(8))) short short8;
typedef __attribute__((ext_vector_type(4))) float f32x4;

__device__ __forceinline__ unsigned pk_bf16(float a, float b) {
    unsigned r;
    asm volatile("v_cvt_pk_bf16_f32 %0, %1, %2" : "=v"(r) : "v"(a), "v"(b));
    return r;
}
__device__ __forceinline__ float bf2f(unsigned short u) {
    unsigned v = ((unsigned)u) << 16;
    return __builtin_bit_cast(float, v);
}

__device__ __forceinline__ void gload_lds16(const void* g, void* l) {
    __builtin_amdgcn_global_load_lds(
        (const __attribute__((address_space(1))) unsigned int*)g,
        (__attribute__((address_space(3))) unsigned int*)l, 16, 0, 0);
}

__device__ __forceinline__ float blockSum(float v, float* sm) {
    v += __shfl_down(v, 32); v += __shfl_down(v, 16); v += __shfl_down(v, 8);
    v += __shfl_down(v, 4);  v += __shfl_down(v, 2);  v += __shfl_down(v, 1);
    __syncthreads();
    if ((threadIdx.x & 63) == 0) sm[threadIdx.x >> 6] = v;
    __syncthreads();
    float r = 0.0f;
    if (threadIdx.x == 0) {
        int nw = blockDim.x >> 6;
        for (int i = 0; i < nw; ++i) r += sm[i];
    }
    return r;
}

// ================= k_pre: fused precompute, uniform grid-stride blocks =================
__global__ __launch_bounds__(256) void k_pre(
        const float* __restrict__ edge_vec, const float* __restrict__ lat,
        const float* __restrict__ apos, const float* __restrict__ kpt,
        const int* __restrict__ esrc, const int* __restrict__ edst,
        const float* __restrict__ hr_gt, const float* __restrict__ hr_pred,
        const float* __restrict__ P_re, const float* __restrict__ P_im,
        const float* __restrict__ Q_re, const float* __restrict__ Q_im,
        const float4* __restrict__ Hg, const float4* __restrict__ Hp,
        const float4* __restrict__ ov, const float4* __restrict__ mk,
        float* __restrict__ phre, float* __restrict__ phim,
        int* __restrict__ bcnt, int* __restrict__ blist,
        unsigned* __restrict__ hrdG,
        unsigned* __restrict__ PpadR, unsigned* __restrict__ PpadI,
        ushort* __restrict__ Prebf, ushort* __restrict__ Pimbf,
        ushort* __restrict__ Qrebf, ushort* __restrict__ Qimbf,
        unsigned* __restrict__ dH, unsigned* __restrict__ ovb,
        float* __restrict__ acc, int compact) {
    __shared__ float sm[8];
    int bid = blockIdx.x;
    int tid = threadIdx.x;

    // ---- phase + buckets (first 6 blocks only) ----
    if (bid < 6) {
        int e = bid*256 + tid;
        if (e < E_N) {
            float a00 = lat[0], a01 = lat[3], a02 = lat[6];
            float a10 = lat[1], a11 = lat[4], a12 = lat[7];
            float a20 = lat[2], a21 = lat[5], a22 = lat[8];
            float c00 = a11*a22 - a12*a21;
            float c01 = a12*a20 - a10*a22;
            float c02 = a10*a21 - a11*a20;
            float det = a00*c00 + a01*c01 + a02*c02;
            float id  = 1.0f / det;
            float i00 = c00*id;
            float i01 = (a02*a21 - a01*a22)*id;
            float i02 = (a01*a12 - a02*a11)*id;
            float i10 = c01*id;
            float i11 = (a00*a22 - a02*a20)*id;
            float i12 = (a02*a10 - a00*a12)*id;
            float i20 = c02*id;
            float i21 = (a01*a20 - a00*a21)*id;
            float i22 = (a00*a11 - a01*a10)*id;
            int s = esrc[e], d = edst[e];
            float r0 = edge_vec[e*3+0] - (apos[d*3+0] - apos[s*3+0]);
            float r1 = edge_vec[e*3+1] - (apos[d*3+1] - apos[s*3+1]);
            float r2 = edge_vec[e*3+2] - (apos[d*3+2] - apos[s*3+2]);
            float t0 = roundf(i00*r0 + i01*r1 + i02*r2);
            float t1 = roundf(i10*r0 + i11*r1 + i12*r2);
            float t2 = roundf(i20*r0 + i21*r1 + i22*r2);
            float ph = t0*kpt[0] + t1*kpt[1] + t2*kpt[2];
            float ang = 6.28318530717958647692f * ph;
            phre[e] = cosf(ang);
            phim[e] = sinf(ang);
            int p = atomicAdd(&bcnt[s], 1);
            if (p < 128) blist[s*128 + p] = (e << 6) | d;
        }
    }

    // ---- section A: hrd = bf16(hr_pred - hr_gt) padded 64x64 swizzled (3 iters) ----
    #pragma unroll
    for (int it = 0; it < 3; ++it) {
        int idx = bid*256 + tid + it*(GRID_PRE*256);   // < 786432 exactly
        int e = idx >> 9;
        int p = idx & 511;
        int i = p >> 3, q = p & 7;
        unsigned outv[4] = {0,0,0,0};
        if (i < 54 && q < 7) {
            const float* g = hr_gt  + (size_t)e*HRSZ + i*54;
            const float* h = hr_pred + (size_t)e*HRSZ + i*54;
            #pragma unroll
            for (int u = 0; u < 4; ++u) {
                int j2 = q*4 + u;
                if (j2 < 27) {
                    float2 gg = *(const float2*)(g + 2*j2);
                    float2 hh = *(const float2*)(h + 2*j2);
                    outv[u] = pk_bf16(hh.x - gg.x, hh.y - gg.y);
                }
            }
        }
        *(uint4*)(hrdG + (size_t)e*2048 + i*32 + ((q ^ (i & 7)) << 2)) =
            make_uint4(outv[0], outv[1], outv[2], outv[3]);
    }

    // ---- section B: red1 sums (+ compact dH/ovb emission), ILP4, 2 iters ----
    {
        float s0 = 0, s1 = 0, s2 = 0;
        #pragma unroll
        for (int it = 0; it < 2; ++it) {
            if (bid*1024 + it*(GRID_PRE*1024) < N4_RED) {
                int b0 = bid*1024 + tid + it*(GRID_PRE*1024);
                float4 hg[4], hp[4], o[4], m[4];
                int val[4];
                #pragma unroll
                for (int u = 0; u < 4; ++u) {
                    int i = b0 + u*256;
                    val[u] = (i < N4_RED);
                    if (val[u]) { hg[u]=Hg[i]; hp[u]=Hp[i]; o[u]=ov[i]; m[u]=mk[i]; }
                    else { hg[u]=float4{0,0,0,0}; hp[u]=hg[u]; o[u]=hg[u]; m[u]=hg[u]; }
                }
                #pragma unroll
                for (int u = 0; u < 4; ++u) {
                    float dx = hp[u].x-hg[u].x, dy = hp[u].y-hg[u].y;
                    float dz = hp[u].z-hg[u].z, dw = hp[u].w-hg[u].w;
                    s0 += dx*o[u].x + dy*o[u].y + dz*o[u].z + dw*o[u].w;
                    s1 += o[u].x*o[u].x + o[u].y*o[u].y + o[u].z*o[u].z + o[u].w*o[u].w;
                    s2 += m[u].x + m[u].y + m[u].z + m[u].w;
                    if (compact && val[u]) {
                        int i = b0 + u*256;
                        *(uint2*)(dH  + (size_t)i*2) = make_uint2(pk_bf16(dx, dy), pk_bf16(dz, dw));
                        *(uint2*)(ovb + (size_t)i*2) = make_uint2(pk_bf16(o[u].x, o[u].y), pk_bf16(o[u].z, o[u].w));
                    }
                }
            }
        }
        float r0 = blockSum(s0, sm);
        float r1 = blockSum(s1, sm);
        float r2 = blockSum(s2, sm);
        if (tid == 0) {
            atomicAdd(&acc[0], r0);
            atomicAdd(&acc[1], r1);
            atomicAdd(&acc[2], r2);
        }
    }

    // ---- section C: pqpad panels + flat bf16 (fused, reads P/Q fp32 once), 2 iters ----
    #pragma unroll
    for (int it = 0; it < 2; ++it) {
        int idx = bid*256 + tid + it*(GRID_PRE*256);
        if (idx < TOT_C) {
            int q = idx & 7;
            int r = idx >> 3;
            int c = r % 640;
            int dst = r / 640;
            const float* sre = (c < NP) ? (P_re + (size_t)c*M_DIM) : (Q_re + (size_t)(c-NP)*M_DIM);
            const float* sim = (c < NP) ? (P_im + (size_t)c*M_DIM) : (Q_im + (size_t)(c-NP)*M_DIM);
            ushort* fre = (c < NP) ? Prebf : Qrebf;
            ushort* fim = (c < NP) ? Pimbf : Qimbf;
            int cc = (c < NP) ? c : c - NP;
            unsigned vr[4] = {0,0,0,0}, vi[4] = {0,0,0,0};
            if (q < 7) {
                #pragma unroll
                for (int u = 0; u < 4; ++u) {
                    int j2 = q*4 + u;
                    if (j2 < 27) {
                        int o = dst*54 + 2*j2;
                        float2 fr = *(const float2*)(sre + o);
                        float2 fi = *(const float2*)(sim + o);
                        vr[u] = pk_bf16(fr.x, fr.y);
                        vi[u] = pk_bf16(fi.x, fi.y);
                        int fo = cc*M_DIM + dst*54 + 2*j2;
                        *(unsigned*)(fre + fo) = vr[u];
                        *(unsigned*)(fim + fo) = vi[u];
                    }
                }
            }
            int loc = (dst*640 + c)*32 + ((q ^ (c & 7)) << 2);
            *(uint4*)(PpadR + loc) = make_uint4(vr[0], vr[1], vr[2], vr[3]);
            *(uint4*)(PpadI + loc) = make_uint4(vi[0], vi[1], vi[2], vi[3]);
        }
    }
}

// ================= k_bp: BP^T via per-edge MFMA, double-buffered =================
__global__ __launch_bounds__(256) void k_bp(
        const unsigned* __restrict__ hrdG,
        const unsigned* __restrict__ PpadR, const unsigned* __restrict__ PpadI,
        const float* __restrict__ phre, const float* __restrict__ phim,
        const int* __restrict__ bcnt, const int* __restrict__ blist,
        ushort* __restrict__ BPTPre, ushort* __restrict__ BPTPim,
        ushort* __restrict__ BPTQre, ushort* __restrict__ BPTQim) {
    __shared__ ushort lds[2][12288];    // 48 KB
    __shared__ int elist[128];
    __shared__ float phs[2][128];

    int tid = threadIdx.x;
    int a   = blockIdx.x / 10;
    int t   = blockIdx.x - a*10;
    ushort *Or, *Oi; int col0;
    if (t < 4) { Or = BPTPre; Oi = BPTPim; col0 = t*64; }
    else       { Or = BPTQre; Oi = BPTQim; col0 = (t-4)*64; }

    int ne = bcnt[a]; if (ne > 128) ne = 128;
    for (int k = tid; k < ne; k += 256) {
        int v = blist[a*128 + k];
        elist[k] = v;
        phs[0][k] = phre[v >> 6];
        phs[1][k] = phim[v >> 6];
    }
    __syncthreads();

    int w = tid >> 6, l = tid & 63;
    int wr0 = (w >> 1)*32, wc0 = (w & 1)*32;
    int lr = l & 15, kq = l >> 4, lk4 = (l >> 4)*4;

    f32x4 accRe[2][2] = {}, accIm[2][2] = {};

    #define ISSUE(nn, bb) do {                                                     \
        int v_ = elist[(nn)];                                                      \
        int ee_ = v_ >> 6, dst_ = v_ & 63;                                         \
        const ushort* g0_ = (const ushort*)(hrdG + (size_t)ee_*2048);              \
        const ushort* g1_ = (const ushort*)(PpadR + ((size_t)dst_*640 + t*64)*32); \
        const ushort* g2_ = (const ushort*)(PpadI + ((size_t)dst_*640 + t*64)*32); \
        ushort* lb_ = &lds[(bb)][0];                                               \
        _Pragma("unroll")                                                          \
        for (int j_ = 0; j_ < 6; ++j_) {                                           \
            int jj_ = w + j_*4;                                                    \
            int arr_ = jj_ >> 3, ch_ = jj_ & 7;                                    \
            const ushort* gb_ = (arr_ == 0) ? g0_ : (arr_ == 1) ? g1_ : g2_;       \
            gload_lds16(gb_ + ch_*512 + l*8, (void*)(lb_ + arr_*4096 + ch_*512));  \
        }                                                                          \
    } while (0)

    if (ne > 0) ISSUE(0, 0);
    for (int n = 0; n < ne; ++n) {
        int cur = n & 1;
        if (n + 1 < ne) {
            ISSUE(n+1, 1-cur);
            asm volatile("s_waitcnt vmcnt(6)" ::: "memory");
        } else {
            asm volatile("s_waitcnt vmcnt(0)" ::: "memory");
        }
        __syncthreads();
        float phr = phs[0][n], phi_ = phs[1][n];
        const ushort* A  = &lds[cur][0];
        const ushort* BR = A + 4096;
        const ushort* BI = A + 8192;
        short8 a0[2], a1[2], br0[2], br1[2], bi0[2], bi1[2];
        #pragma unroll
        for (int mr = 0; mr < 2; ++mr) {
            int r = wr0 + mr*16 + lr;
            a0[mr] = *(const short8*)(A + r*64 + ((kq     ^ (r & 7))<<3));
            a1[mr] = *(const short8*)(A + r*64 + (((4+kq) ^ (r & 7))<<3));
        }
        #pragma unroll
        for (int nc = 0; nc < 2; ++nc) {
            int c = wc0 + nc*16 + lr;
            br0[nc] = *(const short8*)(BR + c*64 + ((kq     ^ (c & 7))<<3));
            br1[nc] = *(const short8*)(BR + c*64 + (((4+kq) ^ (c & 7))<<3));
            bi0[nc] = *(const short8*)(BI + c*64 + ((kq     ^ (c & 7))<<3));
            bi1[nc] = *(const short8*)(BI + c*64 + (((4+kq) ^ (c & 7))<<3));
        }
        f32x4 z = {0.0f, 0.0f, 0.0f, 0.0f};
        f32x4 t1[2][2], t2[2][2];
        #pragma unroll
        for (int mr = 0; mr < 2; ++mr)
            #pragma unroll
            for (int nc = 0; nc < 2; ++nc) {
                t1[mr][nc] = __builtin_amdgcn_mfma_f32_16x16x32_bf16(a0[mr], br0[nc], z, 0, 0, 0);
                t1[mr][nc] = __builtin_amdgcn_mfma_f32_16x16x32_bf16(a1[mr], br1[nc], t1[mr][nc], 0, 0, 0);
                t2[mr][nc] = __builtin_amdgcn_mfma_f32_16x16x32_bf16(a0[mr], bi0[nc], z, 0, 0, 0);
                t2[mr][nc] = __builtin_amdgcn_mfma_f32_16x16x32_bf16(a1[mr], bi1[nc], t2[mr][nc], 0, 0, 0);
            }
        #pragma unroll
        for (int mr = 0; mr < 2; ++mr)
            #pragma unroll
            for (int nc = 0; nc < 2; ++nc)
                #pragma unroll
                for (int q = 0; q < 4; ++q) {
                    accRe[mr][nc][q] += phr*t1[mr][nc][q] - phi_*t2[mr][nc][q];
                    accIm[mr][nc][q] += phr*t2[mr][nc][q] + phi_*t1[mr][nc][q];
                }
        __syncthreads();
    }
    #undef ISSUE

    #pragma unroll
    for (int mr = 0; mr < 2; ++mr)
        #pragma unroll
        for (int nc = 0; nc < 2; ++nc) {
            int ib = wr0 + mr*16 + lk4;
            if (ib < 54) {
                int cg = col0 + wc0 + nc*16 + lr;
                size_t base = (size_t)cg*M_DIM + (size_t)a*54 + ib;
                *(unsigned*)(Or + base) = pk_bf16(accRe[mr][nc][0], accRe[mr][nc][1]);
                *(unsigned*)(Oi + base) = pk_bf16(accIm[mr][nc][0], accIm[mr][nc][1]);
                if (ib + 2 < 54) {
                    *(unsigned*)(Or + base + 2) = pk_bf16(accRe[mr][nc][2], accRe[mr][nc][3]);
                    *(unsigned*)(Oi + base + 2) = pk_bf16(accIm[mr][nc][2], accIm[mr][nc][3]);
                }
            }
        }
}

// ================= k_gemm: bf16 MFMA, 64x64 tile, K-split 6, partial slices =================
#define GPAD 40
__global__ __launch_bounds__(256) void k_gemm(
        const ushort* __restrict__ Prebf, const ushort* __restrict__ Pimbf,
        const ushort* __restrict__ Qrebf, const ushort* __restrict__ Qimbf,
        const ushort* __restrict__ BPTPre, const ushort* __restrict__ BPTPim,
        const ushort* __restrict__ BPTQre, const ushort* __restrict__ BPTQim,
        float* __restrict__ part) {
    __shared__ ushort Ar[64*GPAD], Ai[64*GPAD], Br_[64*GPAD], Bi_[64*GPAD];
    int tid = threadIdx.x;
    int bid = blockIdx.x;
    int t = bid / 6, ks = bid - t*6;
    const ushort *Ag, *Aig, *Bg, *Big; float *Cre, *Cim; int NC, r0, c0;
    if (t < 16) {
        Ag = Prebf; Aig = Pimbf; Bg = BPTPre; Big = BPTPim;
        NC = NP; r0 = (t & 3)*64; c0 = (t >> 2)*64;
        Cre = part + (size_t)ks*2*65536; Cim = Cre + 65536;
    } else if (t < 52) {
        int u = t - 16;
        Ag = Qrebf; Aig = Qimbf; Bg = BPTQre; Big = BPTQim;
        NC = NQ; r0 = (u % 6)*64; c0 = (u / 6)*64;
        Cre = part + 786432 + (size_t)ks*2*147456; Cim = Cre + 147456;
    } else {
        int u = t - 52;
        Ag = Prebf; Aig = Pimbf; Bg = BPTQre; Big = BPTQim;
        NC = NQ; r0 = (u & 3)*64; c0 = (u >> 2)*64;
        Cre = part + 786432 + 1769472 + (size_t)ks*2*98304; Cim = Cre + 98304;
    }
    int k0 = ks * 576;
    int srow = tid >> 2, skq = (tid & 3) * 8;
    int w = tid >> 6, l = tid & 63;
    int wr0 = (w >> 1)*32, wc0 = (w & 1)*32;
    int lr = l & 15, lk = (l >> 4)*8, lk4 = (l >> 4)*4;

    const ushort* pa  = Ag  + (size_t)(r0+srow)*M_DIM + k0 + skq;
    const ushort* pai = Aig + (size_t)(r0+srow)*M_DIM + k0 + skq;
    const ushort* pb  = Bg  + (size_t)(c0+srow)*M_DIM + k0 + skq;
    const ushort* pbi = Big + (size_t)(c0+srow)*M_DIM + k0 + skq;

    short8 ra = *(const short8*)pa, rai = *(const short8*)pai;
    short8 rb = *(const short8*)pb, rbi = *(const short8*)pbi;

    f32x4 aRe[2][2] = {}, aIA[2][2] = {}, aIB[2][2] = {};
    for (int s = 0; s < 18; ++s) {
        __syncthreads();
        *(short8*)(Ar  + srow*GPAD + skq) = ra;
        *(short8*)(Ai  + srow*GPAD + skq) = rai;
        *(short8*)(Br_ + srow*GPAD + skq) = rb;
        *(short8*)(Bi_ + srow*GPAD + skq) = rbi;
        __syncthreads();
        if (s < 17) {
            int o = (s+1)*32;
            ra  = *(const short8*)(pa  + o);
            rai = *(const short8*)(pai + o);
            rb  = *(const short8*)(pb  + o);
            rbi = *(const short8*)(pbi + o);
        }
        short8 fa[2], fn[2], fb[2], fi[2];
        #pragma unroll
        for (int mr = 0; mr < 2; ++mr) {
            int r = wr0 + mr*16 + lr;
            fa[mr] = *(const short8*)(Ar + r*GPAD + lk);
            fn[mr] = *(const short8*)(Ai + r*GPAD + lk);
        }
        #pragma unroll
        for (int nc = 0; nc < 2; ++nc) {
            int c = wc0 + nc*16 + lr;
            fb[nc] = *(const short8*)(Br_ + c*GPAD + lk);
            fi[nc] = *(const short8*)(Bi_ + c*GPAD + lk);
        }
        #pragma unroll
        for (int mr = 0; mr < 2; ++mr)
            #pragma unroll
            for (int nc = 0; nc < 2; ++nc) {
                aRe[mr][nc] = __builtin_amdgcn_mfma_f32_16x16x32_bf16(fa[mr], fb[nc], aRe[mr][nc], 0, 0, 0);
                aRe[mr][nc] = __builtin_amdgcn_mfma_f32_16x16x32_bf16(fn[mr], fi[nc], aRe[mr][nc], 0, 0, 0);
                aIA[mr][nc] = __builtin_amdgcn_mfma_f32_16x16x32_bf16(fa[mr], fi[nc], aIA[mr][nc], 0, 0, 0);
                aIB[mr][nc] = __builtin_amdgcn_mfma_f32_16x16x32_bf16(fn[mr], fb[nc], aIB[mr][nc], 0, 0, 0);
            }
    }
    #pragma unroll
    for (int mr = 0; mr < 2; ++mr)
        #pragma unroll
        for (int nc = 0; nc < 2; ++nc)
            #pragma unroll
            for (int rr = 0; rr < 4; ++rr) {
                int row = r0 + wr0 + mr*16 + lk4 + rr;
                int col = c0 + wc0 + nc*16 + lr;
                Cre[(size_t)row*NC + col] = aRe[mr][nc][rr];
                Cim[(size_t)row*NC + col] = aIA[mr][nc][rr] - aIB[mr][nc][rr];
            }
}

// ================= mu from traces (sum 6 K-partials) =================
__global__ void k_mu(const float* __restrict__ part, float* __restrict__ acc) {
    int t = threadIdx.x;  // 512
    float v1 = 0.0f, v2 = 0.0f;
    if (t < NP) {
        #pragma unroll
        for (int ks = 0; ks < 6; ++ks) v1 += part[ks*131072 + t*(NP+1)];
    }
    if (t < NQ) {
        const float* q = part + 786432;
        #pragma unroll
        for (int ks = 0; ks < 6; ++ks) v2 += q[ks*294912 + t*(NQ+1)];
    }
    __shared__ float sm[8];
    float trP = blockSum(v1, sm);
    float trQ = blockSum(v2, sm);
    if (t == 0) {
        float N1 = acc[2];
        float n1 = W_FR * acc[0] / N1;
        float d1 = W_FR * acc[1] / N1;
        float n2 = W_FP * trP / (float)(NP*NP);
        float n3 = W_FQ * trQ / (float)(NQ*NQ);
        float d2 = W_FP / (float)NP;
        float d3 = W_FQ / (float)NQ;
        acc[3] = (n1 + n2 + n3) / (d1 + d2 + d3);
    }
}

// ================= k_loss: loss_hr + loss_mats =================
__global__ __launch_bounds__(256) void k_loss(
        const float4* __restrict__ Hg, const float4* __restrict__ Hp,
        const float4* __restrict__ ov,
        const uint4* __restrict__ dH, const uint4* __restrict__ ovb,
        const float* __restrict__ part,
        float* __restrict__ acc, int bhr, int compact) {
    __shared__ float sm[8];
    int bid = blockIdx.x;
    int tid = threadIdx.x;
    float mu = acc[3];
    if (bid < bhr) {
        float s = 0;
        if (compact) {
            const int N8 = E_N*HRSZ/8;    // 559872
            int b0 = bid*1024 + tid;
            #pragma unroll
            for (int u = 0; u < 4; ++u) {
                int i8 = b0 + u*256;
                if (i8 < N8) {
                    uint4 dv = dH[i8];
                    uint4 o4 = ovb[i8];
                    unsigned dd[4] = {dv.x, dv.y, dv.z, dv.w};
                    unsigned oo[4] = {o4.x, o4.y, o4.z, o4.w};
                    #pragma unroll
                    for (int p = 0; p < 4; ++p) {
                        float d0 = bf2f((unsigned short)(dd[p] & 0xffffu));
                        float d1 = bf2f((unsigned short)(dd[p] >> 16));
                        float o0 = bf2f((unsigned short)(oo[p] & 0xffffu));
                        float o1 = bf2f((unsigned short)(oo[p] >> 16));
                        s += fabsf(mu*o0 - d0) + fabsf(mu*o1 - d1);
                    }
                }
            }
        } else {
            const int N4 = E_N*HRSZ/4;
            int b0 = bid*1024 + tid;
            #pragma unroll
            for (int u = 0; u < 4; ++u) {
                int i = b0 + u*256;
                if (i < N4) {
                    float4 hg = Hg[i], hp = Hp[i], o = ov[i];
                    s += fabsf(hg.x + mu*o.x - hp.x) + fabsf(hg.y + mu*o.y - hp.y)
                       + fabsf(hg.z + mu*o.z - hp.z) + fabsf(hg.w + mu*o.w - hp.w);
                }
            }
        }
        float r = blockSum(s, sm);
        if (tid == 0) atomicAdd(&acc[4], r);
    } else {
        const int NPP = NP*NP, NQQ = NQ*NQ, NPQ = NP*NQ;
        float sP = 0, sQ = 0, sPQ = 0;
        int stride = 256*256;
        for (int i = (bid - bhr)*256 + tid; i < NPP+NQQ+NPQ; i += stride) {
            if (i < NPP) {
                float sre = 0, sim = 0;
                #pragma unroll
                for (int ks = 0; ks < 6; ++ks) {
                    sre += part[ks*131072 + i];
                    sim += part[ks*131072 + 65536 + i];
                }
                int r = i >> 8, c = i & 255;
                float d = (r == c) ? mu : 0.0f;
                sP += fabsf(d - sre) + fabsf(sim);
            } else if (i < NPP+NQQ) {
                int j = i - NPP;
                const float* q = part + 786432;
                float sre = 0, sim = 0;
                #pragma unroll
                for (int ks = 0; ks < 6; ++ks) {
                    sre += q[ks*294912 + j];
                    sim += q[ks*294912 + 147456 + j];
                }
                int r = j / NQ, c = j - r*NQ;
                float d = (r == c) ? mu : 0.0f;
                sQ += fabsf(d - sre) + fabsf(sim);
            } else {
                int j = i - (NPP+NQQ);
                const float* pq = part + 786432 + 1769472;
                float sre = 0, sim = 0;
                #pragma unroll
                for (int ks = 0; ks < 6; ++ks) {
                    sre += pq[ks*196608 + j];
                    sim += pq[ks*196608 + 98304 + j];
                }
                sPQ += fabsf(sre) + fabsf(sim);
            }
        }
        float a1 = blockSum(sP, sm);
        float a2 = blockSum(sQ, sm);
        float a3 = blockSum(sPQ, sm);
        if (tid == 0) {
            atomicAdd(&acc[5], a1);
            atomicAdd(&acc[6], a2);
            atomicAdd(&acc[7], a3);
        }
    }
}

// ================= final combine =================
__global__ void k_final(const float* __restrict__ acc, float* __restrict__ out) {
    if (threadIdx.x == 0 && blockIdx.x == 0) {
        float N1 = acc[2];
        out[0] = W_FR*acc[4]/N1
               + W_FP*acc[5]/(float)(NP*NP)
               + W_FQ*acc[6]/(float)(NQ*NQ)
               + W_FO*acc[7]/(float)(NP*NQ);
    }
}

extern "C" void kernel_launch(void* const* d_in, const int* in_sizes, int n_in,
                              void* d_out, int out_size, void* d_ws, size_t ws_size,
                              hipStream_t stream) {
    const float* edge_vec = (const float*)d_in[0];
    const float* lattice  = (const float*)d_in[1];
    const float* apos     = (const float*)d_in[2];
    const float* hr_gt    = (const float*)d_in[3];
    const float* hr_pred  = (const float*)d_in[4];
    const float* kpt      = (const float*)d_in[5];
    const float* P_re     = (const float*)d_in[6];
    const float* P_im     = (const float*)d_in[7];
    const float* Q_re     = (const float*)d_in[8];
    const float* Q_im     = (const float*)d_in[9];
    const float* H_gt     = (const float*)d_in[10];
    const float* pred_H   = (const float*)d_in[11];
    const float* overlap  = (const float*)d_in[12];
    const float* mask     = (const float*)d_in[13];
    const int*   esrc     = (const int*)d_in[14];
    const int*   edst     = (const int*)d_in[15];
    float* out = (float*)d_out;

    float* ws   = (float*)d_ws;
    float* acc  = ws;                         // 16 f
    int*   bcnt = (int*)(ws + 16);            // 64 int
    int*   blist= (int*)(ws + 80);            // 64*128 int
    float* phre = ws + 8272;
    float* phim = phre + E_N;
    ushort* us  = (ushort*)(ws + 16384);      // byte 65536
    ushort* Prebf  = us;
    ushort* Pimbf  = Prebf  + (size_t)NP*M_DIM;
    ushort* Qrebf  = Pimbf  + (size_t)NP*M_DIM;
    ushort* Qimbf  = Qrebf  + (size_t)NQ*M_DIM;
    ushort* BPTPre = Qimbf  + (size_t)NQ*M_DIM;
    ushort* BPTPim = BPTPre + (size_t)NP*M_DIM;
    ushort* BPTQre = BPTPim + (size_t)NP*M_DIM;
    ushort* BPTQim = BPTQre + (size_t)NQ*M_DIM;
    unsigned* PpadR = (unsigned*)(BPTQim + (size_t)NQ*M_DIM);
    unsigned* PpadI = PpadR + (size_t)64*640*32;
    unsigned* hrdG  = PpadI + (size_t)64*640*32;                   // 12.58 MB
    float* part = (float*)hrdG;               // aliased (k_gemm after k_bp); 14.94 MB
    // compact residual buffers after part's end
    size_t part_end_bytes = ((char*)part - (char*)d_ws) + (size_t)3735552*4;
    unsigned* dH  = (unsigned*)((char*)d_ws + part_end_bytes);     // E*HRSZ bf16 = 8.96 MB
    unsigned* ovb = dH + (size_t)E_N*HRSZ/2;
    size_t need = part_end_bytes + 2*(size_t)E_N*HRSZ*2;
    int compact = (ws_size >= need) ? 1 : 0;

    hipMemsetAsync(ws, 0, 320, stream);   // acc + bcnt

    k_pre<<<GRID_PRE, 256, 0, stream>>>(edge_vec, lattice, apos, kpt, esrc, edst,
                                        hr_gt, hr_pred, P_re, P_im, Q_re, Q_im,
                                        (const float4*)H_gt, (const float4*)pred_H,
                                        (const float4*)overlap, (const float4*)mask,
                                        phre, phim, bcnt, blist,
                                        hrdG, PpadR, PpadI,
                                        Prebf, Pimbf, Qrebf, Qimbf,
                                        dH, ovb, acc, compact);
    k_bp<<<NATOMS*10, 256, 0, stream>>>(hrdG, PpadR, PpadI, phre, phim, bcnt, blist,
                                        BPTPre, BPTPim, BPTQre, BPTQim);
    k_gemm<<<456, 256, 0, stream>>>(Prebf, Pimbf, Qrebf, Qimbf,
                                    BPTPre, BPTPim, BPTQre, BPTQim, part);
    k_mu<<<1, 512, 0, stream>>>(part, acc);
    int bhr = compact ? 547 : 1094;
    k_loss<<<bhr + 256, 256, 0, stream>>>((const float4*)H_gt, (const float4*)pred_H,
                                          (const float4*)overlap,
                                          (const uint4*)dH, (const uint4*)ovb,
                                          part, acc, bhr, compact);
    k_final<<<1, 1, 0, stream>>>(acc, out);
}